// Round 10
// baseline (86.717 us; speedup 1.0000x reference)
//
#include <hip/hip_runtime.h>

typedef __attribute__((ext_vector_type(8))) short bf16x8;
typedef __attribute__((ext_vector_type(4))) float f32x4;
typedef unsigned short u16;
typedef unsigned int u32;

constexpr int N = 8192;
constexpr int D = 128;
constexpr float CEXP   = 2.8853900817779268f;  // log2(e)/tau, tau = 0.5
constexpr float BSCALE = 1.6986435688113073f;  // sqrt(CEXP) folded into bf16 inputs

#if __has_builtin(__builtin_amdgcn_exp2f)
__device__ __forceinline__ float fexp2(float x) { return __builtin_amdgcn_exp2f(x); }
#else
__device__ __forceinline__ float fexp2(float x) { return exp2f(x); }
#endif

__device__ __forceinline__ u32 f2bf(float x) {
  union { float f; unsigned u; } v;
  v.f = x;
  unsigned r = v.u + 0x7fffu + ((v.u >> 16) & 1u);  // RNE
  return r >> 16;
}

// ---------- fused: fp32->bf16 convert (pre-scaled) + per-row exact dots + zero accums ----------
__global__ void convert_dots_kernel(const float2* __restrict__ z1, const float2* __restrict__ z2,
                                    u32* __restrict__ o1, u32* __restrict__ o2,
                                    float* __restrict__ dotSelf, float* __restrict__ dotCross,
                                    float* __restrict__ zeroBase, float* __restrict__ out) {
  const int tid = threadIdx.x;
  const int row = blockIdx.x * 4 + (tid >> 6);
  const int l = tid & 63;
  const int zidx = blockIdx.x * 256 + tid;
  if (zidx < 3 * N) zeroBase[zidx] = 0.0f;  // rowRefl | rowBet | colBet
  if (zidx == 0) out[0] = 0.0f;

  float2 a = z1[row * 64 + l];
  float2 b = z2[row * 64 + l];
  o1[row * 64 + l] = f2bf(a.x * BSCALE) | (f2bf(a.y * BSCALE) << 16);
  o2[row * 64 + l] = f2bf(b.x * BSCALE) | (f2bf(b.y * BSCALE) << 16);

  float d11 = a.x * a.x + a.y * a.y;
  float d12 = a.x * b.x + a.y * b.y;
#pragma unroll
  for (int mask = 1; mask < 64; mask <<= 1) {
    d11 += __shfl_xor(d11, mask);
    d12 += __shfl_xor(d12, mask);
  }
  if (l == 0) {
    dotSelf[row] = d11;
    dotCross[row] = d12;
  }
}

// ---------- helpers (array-ref inline: no copies, constant indexing only) ----------
__device__ __forceinline__ void mfma_tile(const bf16x8 (&af)[4][4], const bf16x8 (&bf)[4],
                                          f32x4 (&acc)[4]) {
  const f32x4 z4 = {0.f, 0.f, 0.f, 0.f};
#pragma unroll
  for (int m = 0; m < 4; ++m)
    acc[m] = __builtin_amdgcn_mfma_f32_16x16x32_bf16(af[m][0], bf[0], z4, 0, 0, 0);
#pragma unroll
  for (int kk = 1; kk < 4; ++kk)
#pragma unroll
    for (int m = 0; m < 4; ++m)
      acc[m] = __builtin_amdgcn_mfma_f32_16x16x32_bf16(af[m][kk], bf[kk], acc[m], 0, 0, 0);
}

__device__ __forceinline__ void epi_refl(const f32x4 (&acc)[4], float (&rowp)[4][4]) {
#pragma unroll
  for (int m = 0; m < 4; ++m)
#pragma unroll
    for (int r = 0; r < 4; ++r) rowp[m][r] += fexp2(acc[m][r]);
}

__device__ __forceinline__ void epi_bet(const f32x4 (&acc)[4], float (&rowp)[4][4],
                                        float* __restrict__ colBet, int cbase, int l) {
  float colp = 0.f;
#pragma unroll
  for (int m = 0; m < 4; ++m) {
    float v0 = fexp2(acc[m][0]), v1 = fexp2(acc[m][1]);
    float v2 = fexp2(acc[m][2]), v3 = fexp2(acc[m][3]);
    rowp[m][0] += v0;
    rowp[m][1] += v1;
    rowp[m][2] += v2;
    rowp[m][3] += v3;
    colp += (v0 + v1) + (v2 + v3);
  }
  colp += __shfl_xor(colp, 16);  // reduce over lane-groups (rows)
  colp += __shfl_xor(colp, 32);
  if (l < 16) atomicAdd(&colBet[cbase + l], colp);
}

#define LOADF(SET, P, OFF)                         \
  SET[0] = *(const bf16x8*)((P) + (OFF));          \
  SET[1] = *(const bf16x8*)((P) + (OFF) + 64);     \
  SET[2] = *(const bf16x8*)((P) + (OFF) + 128);    \
  SET[3] = *(const bf16x8*)((P) + (OFF) + 192)

// ---------- fused GEMM + exp + row/col sums; refl+between in one pass ----------
// grid: 1024 = bi(128: 64 A-rows) x jg(8: 1024 cols). Wave w streams cols
// jg*1024 + w*16 + s*64 (s=0..15) of BOTH z1b (refl) and z2b (between), B fragments
// straight from L2 with named-set ping-pong register prefetch (no LDS, no barriers,
// no hot-loop atomco-waits). launch_bounds(256,2): ~190 unified regs, zero spill.
__global__ __launch_bounds__(256, 2) void gemm_kernel(const u16* __restrict__ z1b,
                                                      const u16* __restrict__ z2b,
                                                      float* __restrict__ rowRefl,
                                                      float* __restrict__ rowBet,
                                                      float* __restrict__ colBet) {
  __shared__ __align__(16) char Abuf[16384];
  const int tid = threadIdx.x;
  const int l = tid & 63, w = tid >> 6;
  const int lr = l & 15, lg = l >> 4;
  const int bi = blockIdx.x >> 3;
  const int jg = blockIdx.x & 7;
  const int col0 = jg * 1024 + w * 16;  // this wave's first col (step 64 per strip)

  // ---- A prologue (verbatim R7/R9, proven): stage 16KB, read af through swizzle ----
  {
    const int soff = (tid >> 4) * 256 + (((tid & 15) ^ (tid >> 4)) << 4);
    const char* gA = (const char*)(z1b + (size_t)bi * 64 * D);
#pragma unroll
    for (int s = 0; s < 4; ++s) {
      __builtin_amdgcn_global_load_lds(
          (const __attribute__((address_space(1))) u32*)(gA + soff + s * 4096),
          (__attribute__((address_space(3))) u32*)(Abuf + tid * 16 + s * 4096), 16, 0, 0);
    }
  }
  __syncthreads();
  bf16x8 af[4][4];  // [m][kk]: row = bi*64 + m*16 + lr, k = kk*32 + lg*8
#pragma unroll
  for (int m = 0; m < 4; ++m)
#pragma unroll
    for (int kk = 0; kk < 4; ++kk)
      af[m][kk] = *(const bf16x8*)(Abuf + (m * 16 + lr) * 256 + (((kk * 4 + lg) ^ lr) << 4));
  __syncthreads();
  // clobber: aliasing store pins af in registers (no sinking of the ds_reads)
  *(u32*)(Abuf + ((tid * 64) & 16383)) = 0u;

  float rowp1[4][4], rowp2[4][4];
#pragma unroll
  for (int m = 0; m < 4; ++m)
#pragma unroll
    for (int r = 0; r < 4; ++r) {
      rowp1[m][r] = 0.f;
      rowp2[m][r] = 0.f;
    }

  // per-lane B base: col-row lr, k-chunk lg; strip stride 16KB (64 cols x 256B)
  const char* p1 = (const char*)z1b + (size_t)(col0 + lr) * 256 + lg * 16;
  const char* p2 = (const char*)z2b + (size_t)(col0 + lr) * 256 + lg * 16;

  bf16x8 X1[4], X2[4], Y1[4], Y2[4];
  LOADF(X1, p1, 0);  // prologue: strip 0
  LOADF(X2, p2, 0);

  int cb = col0;  // colBet base for the current even strip
  for (int k = 0; k < 7; ++k) {
    LOADF(Y1, p1, 16384);  // prefetch strip 2k+1 (covered by strip-2k compute)
    LOADF(Y2, p2, 16384);
    {
      f32x4 acc[4];
      mfma_tile(af, X1, acc);
      epi_refl(acc, rowp1);
    }
    {
      f32x4 acc[4];
      mfma_tile(af, X2, acc);
      epi_bet(acc, rowp2, colBet, cb, l);
    }
    LOADF(X1, p1, 32768);  // prefetch strip 2k+2 (covered by strip-2k+1 compute)
    LOADF(X2, p2, 32768);
    {
      f32x4 acc[4];
      mfma_tile(af, Y1, acc);
      epi_refl(acc, rowp1);
    }
    {
      f32x4 acc[4];
      mfma_tile(af, Y2, acc);
      epi_bet(acc, rowp2, colBet, cb + 64, l);
    }
    p1 += 32768;
    p2 += 32768;
    cb += 128;
  }
  // tail: strips 14 (in X) and 15
  LOADF(Y1, p1, 16384);
  LOADF(Y2, p2, 16384);
  {
    f32x4 acc[4];
    mfma_tile(af, X1, acc);
    epi_refl(acc, rowp1);
  }
  {
    f32x4 acc[4];
    mfma_tile(af, X2, acc);
    epi_bet(acc, rowp2, colBet, cb, l);
  }
  {
    f32x4 acc[4];
    mfma_tile(af, Y1, acc);
    epi_refl(acc, rowp1);
  }
  {
    f32x4 acc[4];
    mfma_tile(af, Y2, acc);
    epi_bet(acc, rowp2, colBet, cb + 64, l);
  }

  // ---- deferred row reductions: shuffle over the 16 col-lanes, one atomic per row ----
#pragma unroll
  for (int m = 0; m < 4; ++m)
#pragma unroll
    for (int r = 0; r < 4; ++r) {
      float s1 = rowp1[m][r];
      float s2 = rowp2[m][r];
      s1 += __shfl_xor(s1, 1);
      s2 += __shfl_xor(s2, 1);
      s1 += __shfl_xor(s1, 2);
      s2 += __shfl_xor(s2, 2);
      s1 += __shfl_xor(s1, 4);
      s2 += __shfl_xor(s2, 4);
      s1 += __shfl_xor(s1, 8);
      s2 += __shfl_xor(s2, 8);
      if (lr == 0) {
        const int rowi = bi * 64 + m * 16 + lg * 4 + r;
        atomicAdd(&rowRefl[rowi], s1);
        atomicAdd(&rowBet[rowi], s2);
      }
    }
}

// ---------- per-row loss (exact fp32 diagonals) + mean ----------
__global__ void final_kernel(const float* __restrict__ rowRefl, const float* __restrict__ rowBet,
                             const float* __restrict__ colBet, const float* __restrict__ dotSelf,
                             const float* __restrict__ dotCross, float* __restrict__ out) {
  const int r = blockIdx.x * 256 + threadIdx.x;
  float rdiag = fexp2(dotSelf[r] * CEXP);
  float base = rowRefl[r] - rdiag;
  float loss = 0.5f * (logf(base + rowBet[r]) + logf(base + colBet[r])) - 2.0f * dotCross[r];
  loss *= (1.0f / (float)N);
#pragma unroll
  for (int mask = 1; mask < 64; mask <<= 1) loss += __shfl_xor(loss, mask);
  if ((threadIdx.x & 63) == 0) atomicAdd(out, loss);
}

extern "C" void kernel_launch(void* const* d_in, const int* in_sizes, int n_in,
                              void* d_out, int out_size, void* d_ws, size_t ws_size,
                              hipStream_t stream) {
  const float* z1 = (const float*)d_in[0];
  const float* z2 = (const float*)d_in[1];
  float* out = (float*)d_out;
  char* ws = (char*)d_ws;

  // ws: z1b(2MB) | z2b(2MB) | rowRefl(N) | rowBet(N) | colBet(N) | dotSelf(N) | dotCross(N)
  u16* z1b = (u16*)ws;
  u16* z2b = (u16*)(ws + (size_t)N * D * 2);
  float* rowRefl = (float*)(ws + (size_t)2 * N * D * 2);
  float* rowBet = rowRefl + N;
  float* colBet = rowBet + N;
  float* dotSelf = colBet + N;
  float* dotCross = dotSelf + N;

  convert_dots_kernel<<<N / 4, 256, 0, stream>>>((const float2*)z1, (const float2*)z2,
                                                 (u32*)z1b, (u32*)z2b, dotSelf, dotCross,
                                                 rowRefl, out);
  gemm_kernel<<<1024, 256, 0, stream>>>(z1b, z2b, rowRefl, rowBet, colBet);
  final_kernel<<<N / 256, 256, 0, stream>>>(rowRefl, rowBet, colBet, dotSelf, dotCross, out);
}